// Round 5
// baseline (5342.904 us; speedup 1.0000x reference)
//
#include <hip/hip_runtime.h>

#define HH 1024
#define FOURH 4096
#define BB 256
#define TT 192
#define WARM 64
#define NSTEP 256        // 128 warm + 127 decode + 1 final-output-only iteration
#define UPB 16           // units per block
#define LDS_BYTES 150144

typedef _Float16 f16;
typedef _Float16 f16x4 __attribute__((ext_vector_type(4)));
typedef _Float16 f16x8 __attribute__((ext_vector_type(8)));
typedef float    f32x4 __attribute__((ext_vector_type(4)));
typedef unsigned long long u64;

// workspace layout (bytes):
//   [0, 1 MiB)      : h ping-pong buffers, f16 [2][256][1024]
//   [1 MiB, +1 KiB) : per-block step flags (256 u32, monotonic = step+1)
//   [+1 KiB, +256K) : pred partials f32 [2][4 mg][64 row][2 k][64 nblk]
#define H_ELEMS (BB*HH)
#define FLG_OFF (2*H_ELEMS*2)
#define PP_OFF  (FLG_OFF + 1024)

__global__ void init_ws(unsigned int* ws) {
  int i = blockIdx.x * 256 + threadIdx.x;
  if (i < (FLG_OFF + 1024) / 4) ws[i] = 0u;
}

__device__ __forceinline__ float fsig(float x) { return 1.0f / (1.0f + __expf(-x)); }
__device__ __forceinline__ float ftanh(float x) {
  float ax = fabsf(x);
  float e  = __expf(-2.0f * ax);
  float t  = (1.0f - e) / (1.0f + e);
  return x < 0.0f ? -t : t;
}

// cache-bypassing accessors — ONLY for flags and write-through stores
__device__ __forceinline__ u64 cld64(const void* p) {
  return __hip_atomic_load((const u64*)p, __ATOMIC_RELAXED, __HIP_MEMORY_SCOPE_AGENT);
}
__device__ __forceinline__ void cst32(void* p, unsigned int v) {
  __hip_atomic_store((unsigned int*)p, v, __ATOMIC_RELAXED, __HIP_MEMORY_SCOPE_AGENT);
}
__device__ __forceinline__ void cstf(float* p, float v) {
  __hip_atomic_store(p, v, __ATOMIC_RELAXED, __HIP_MEMORY_SCOPE_AGENT);
}
__device__ __forceinline__ unsigned int umin4(unsigned int a, unsigned int b,
                                              unsigned int c, unsigned int d) {
  unsigned int x = a < b ? a : b;
  unsigned int y = c < d ? c : d;
  return x < y ? x : y;
}

__launch_bounds__(256, 1)
__global__ void lstm_persist(const float* __restrict__ inp,
                             const float* __restrict__ Wx,
                             const float* __restrict__ Wh,
                             const float* __restrict__ bias,
                             const float* __restrict__ Wd,
                             const float* __restrict__ bdp,
                             float* __restrict__ out,
                             unsigned char* __restrict__ ws)
{
  extern __shared__ char smem[];
  f16*   Wl     = (f16*)smem;                    // 65536 halfs = 128 KiB, B-frag swizzled
  float* z_lds  = (float*)(smem + 131072);       // 64 x 68 fp32
  float* x_sh   = z_lds + 64 * 68;               // 64 x 2
  float* mask_sh= x_sh + 128;                    // 64
  float* wx0_sh = mask_sh + 64;                  // 64
  float* wx1_sh = wx0_sh + 64;                   // 64
  float* b_sh   = wx1_sh + 64;                   // 64
  float* wd_sh  = b_sh + 64;                     // 32

  f16*          hbuf = (f16*)ws;
  unsigned int* flg  = (unsigned int*)(ws + FLG_OFF);
  float*        pp   = (float*)(ws + PP_OFF);

  const int tid  = threadIdx.x;
  const int bx   = blockIdx.x;
  const int mg   = bx >> 6;         // 4 batch groups of 64 rows
  const int nblk = bx & 63;         // 64 unit-groups of 16 units
  const int ublk = nblk * UPB;

  // ---------------- prologue: stage Wh slice into LDS in B-fragment order ----------------
  {
    const int wrow = tid >> 6;           // 0..3
    const int l    = tid & 63;
    const int gate = l >> 4;             // 0..3
    const int u    = l & 15;
    const int gcol = gate * HH + ublk + u;
    for (int rb = 0; rb < 256; rb += 8) {
      float v[8];
#pragma unroll
      for (int ii = 0; ii < 8; ++ii) {
        int r = (rb + ii) * 4 + wrow;
        v[ii] = Wh[r * FOURH + gcol];
      }
#pragma unroll
      for (int ii = 0; ii < 8; ++ii) {
        int r = (rb + ii) * 4 + wrow;
        int kk = r >> 5, sub = r & 31, q = sub >> 3, j = sub & 7;
        // frag layout: B[k = 32*kk + 8*q + j][n = u] for n-frag 'gate'
        Wl[((kk * 4 + gate) * 64 + (q * 16 + u)) * 8 + j] = (f16)v[ii];
      }
    }
    if (tid < 64) {
      int g2 = tid >> 4, u2 = tid & 15;
      int gc = g2 * HH + ublk + u2;
      wx0_sh[tid] = Wx[gc];
      wx1_sh[tid] = Wx[FOURH + gc];
      b_sh[tid]   = bias[gc];
    }
    if (tid < UPB) {
      wd_sh[tid * 2 + 0] = Wd[(ublk + tid) * 2 + 0];
      wd_sh[tid * 2 + 1] = Wd[(ublk + tid) * 2 + 1];
    }
  }
  __syncthreads();

  // per-thread cell state (phase C ownership): unit u_ep, rows r0 + 16q
  const int u_ep = tid & 15;
  const int r0   = tid >> 4;
  float c_reg[4] = {0.f, 0.f, 0.f, 0.f};
  float h_reg[4] = {0.f, 0.f, 0.f, 0.f};

  const int wid  = tid >> 6;
  const int kh   = wid >> 1;           // k-half: 0 -> k[0,512), 1 -> k[512,1024)
  const int mh   = wid & 1;            // row-half: 0 -> rows 0..31, 1 -> rows 32..63
  const int lane = tid & 63;
  const int lm   = lane & 15;
  const int lq   = lane >> 4;

  const float bd0 = bdp[0], bd1 = bdp[1];

  for (int s = 0; s < NSTEP; ++s) {
    const bool decode = (s >= 128);

    // -------- coherence acquire: drop (clean) L1+L2 lines so cached loads see the
    // -------- write-through data produced before the grid barrier. All kernel global
    // -------- writes are write-through, so no dirty lines can be lost.
    asm volatile("buffer_inv sc1\n\ts_waitcnt vmcnt(0)" ::: "memory");

    const f16* hb    = hbuf + (s & 1) * H_ELEMS;
    f16*       hnext = hbuf + ((s + 1) & 1) * H_ELEMS;

    // ---------------- phase A: pred-partial loads (decode, all 256 threads) -------------
    const int prow = tid >> 2;           // 0..63
    const int pk   = (tid >> 1) & 1;     // output dim
    const int ph   = tid & 1;            // half of the 64 partials
    if (decode) {
      const float* p = pp + ((((s + 1) & 1) * 4 + mg) * 64 + prow) * 128 + pk * 64 + ph * 32;
      f32x4 pv0 = *(const f32x4*)(p);
      f32x4 pv1 = *(const f32x4*)(p + 4);
      f32x4 pv2 = *(const f32x4*)(p + 8);
      f32x4 pv3 = *(const f32x4*)(p + 12);
      f32x4 pv4 = *(const f32x4*)(p + 16);
      f32x4 pv5 = *(const f32x4*)(p + 20);
      f32x4 pv6 = *(const f32x4*)(p + 24);
      f32x4 pv7 = *(const f32x4*)(p + 28);
      f32x4 t0 = pv0 + pv1, t1 = pv2 + pv3, t2 = pv4 + pv5, t3 = pv6 + pv7;
      f32x4 t  = (t0 + t1) + (t2 + t3);
      float r  = (t.x + t.y) + (t.z + t.w);
      r += __shfl_xor(r, 1, 64);         // combine the two halves (tid, tid^1)
      if (ph == 0) {
        float pr = r + (pk ? bd1 : bd0);
        x_sh[prow * 2 + pk] = pr;
        if (nblk == 0) cstf(&out[((mg * 64 + prow) * 128 + (s - 128)) * 2 + pk], pr);
      }
      if (s == NSTEP - 1) break;   // uniform across the whole grid
    } else {
      if (tid < 64) {
        int row = tid;
        const float* ip = inp + ((mg * 64 + row) * TT + (WARM + s)) * 2;
        float i0 = ip[0], i1 = ip[1];
        bool m = (i0 != -1.0f) || (i1 != -1.0f);
        x_sh[row * 2 + 0] = m ? i0 : 0.0f;
        x_sh[row * 2 + 1] = m ? i1 : 0.0f;
        mask_sh[row]      = m ? 1.0f : 0.0f;
      }
    }

    // ---------------- phase B: partial z over this wave's (row-half, k-half) ------------
    // A-frags via plain cached 16B loads (L1/L2 hit after first line touch); B from LDS.
    f32x4 acc[2][4];
#pragma unroll
    for (int m = 0; m < 2; ++m)
#pragma unroll
      for (int n = 0; n < 4; ++n) acc[m][n] = f32x4{0.f, 0.f, 0.f, 0.f};

    const f16* abase0 = hb + (mg * 64 + 32 * mh +  0 + lm) * HH + 512 * kh + 8 * lq;
    const f16* abase1 = abase0 + 16 * HH;

#pragma unroll
    for (int ks = 0; ks < 16; ++ks) {
      f16x8 a0 = *(const f16x8*)(abase0 + 32 * ks);
      f16x8 a1 = *(const f16x8*)(abase1 + 32 * ks);
      const f16* bb = Wl + (16 * kh + ks) * 2048 + lane * 8;
      f16x8 b0 = *(const f16x8*)(bb);
      f16x8 b1 = *(const f16x8*)(bb + 512);
      f16x8 b2 = *(const f16x8*)(bb + 1024);
      f16x8 b3 = *(const f16x8*)(bb + 1536);
      acc[0][0] = __builtin_amdgcn_mfma_f32_16x16x32_f16(a0, b0, acc[0][0], 0, 0, 0);
      acc[0][1] = __builtin_amdgcn_mfma_f32_16x16x32_f16(a0, b1, acc[0][1], 0, 0, 0);
      acc[0][2] = __builtin_amdgcn_mfma_f32_16x16x32_f16(a0, b2, acc[0][2], 0, 0, 0);
      acc[0][3] = __builtin_amdgcn_mfma_f32_16x16x32_f16(a0, b3, acc[0][3], 0, 0, 0);
      acc[1][0] = __builtin_amdgcn_mfma_f32_16x16x32_f16(a1, b0, acc[1][0], 0, 0, 0);
      acc[1][1] = __builtin_amdgcn_mfma_f32_16x16x32_f16(a1, b1, acc[1][1], 0, 0, 0);
      acc[1][2] = __builtin_amdgcn_mfma_f32_16x16x32_f16(a1, b2, acc[1][2], 0, 0, 0);
      acc[1][3] = __builtin_amdgcn_mfma_f32_16x16x32_f16(a1, b3, acc[1][3], 0, 0, 0);
    }

    // ---------------- z merge: kh=0 plain store, barrier, kh=1 read-add-write -----------
    // C/D layout: row = 32*mh + 16*m + 4*lq + reg, col = 16*n + lm  (race-free by rows)
    if (kh == 0) {
#pragma unroll
      for (int m = 0; m < 2; ++m) {
        const int rb = 32 * mh + 16 * m + 4 * lq;
#pragma unroll
        for (int n = 0; n < 4; ++n) {
          const int cb = 16 * n + lm;
#pragma unroll
          for (int r = 0; r < 4; ++r)
            z_lds[(rb + r) * 68 + cb] = acc[m][n][r];
        }
      }
    }
    __syncthreads();
    if (kh == 1) {
#pragma unroll
      for (int m = 0; m < 2; ++m) {
        const int rb = 32 * mh + 16 * m + 4 * lq;
#pragma unroll
        for (int n = 0; n < 4; ++n) {
          const int cb = 16 * n + lm;
#pragma unroll
          for (int r = 0; r < 4; ++r)
            z_lds[(rb + r) * 68 + cb] += acc[m][n][r];
        }
      }
    }
    __syncthreads();

    // ---------------- phase C: gates + state update + pred partials ----------------
    const bool wr_pred = (s >= 127);
#pragma unroll
    for (int q4 = 0; q4 < 4; ++q4) {
      int row = r0 + 16 * q4;
      float x0 = x_sh[row * 2], x1 = x_sh[row * 2 + 1];
      float* zr = z_lds + row * 68;
      float zi = zr[     u_ep] + x0 * wx0_sh[     u_ep] + x1 * wx1_sh[     u_ep] + b_sh[     u_ep];
      float zf = zr[16 + u_ep] + x0 * wx0_sh[16 + u_ep] + x1 * wx1_sh[16 + u_ep] + b_sh[16 + u_ep];
      float zg = zr[32 + u_ep] + x0 * wx0_sh[32 + u_ep] + x1 * wx1_sh[32 + u_ep] + b_sh[32 + u_ep];
      float zo = zr[48 + u_ep] + x0 * wx0_sh[48 + u_ep] + x1 * wx1_sh[48 + u_ep] + b_sh[48 + u_ep];
      float ig = fsig(zi), fg = fsig(zf), gg = ftanh(zg), og = fsig(zo);
      float cn = fg * c_reg[q4] + ig * gg;
      float hn = og * ftanh(cn);
      if (!decode) {
        bool m = mask_sh[row] > 0.5f;
        cn = m ? cn : c_reg[q4];
        hn = m ? hn : h_reg[q4];
      }
      c_reg[q4] = cn; h_reg[q4] = hn;

      // packed write-through h store (2 halfs per u32, even lanes store)
      f16 hf = (f16)hn;
      unsigned int lo16    = (unsigned int)__builtin_bit_cast(unsigned short, hf);
      unsigned int partner = (unsigned int)__shfl_xor((int)lo16, 1, 64);
      if ((u_ep & 1) == 0) {
        unsigned int pair = lo16 | (partner << 16);
        cst32((void*)(hnext + (mg * 64 + row) * HH + ublk + u_ep), pair);
      }

      if (wr_pred) {
        float p0 = hn * wd_sh[u_ep * 2 + 0];
        float p1 = hn * wd_sh[u_ep * 2 + 1];
#pragma unroll
        for (int m2 = 1; m2 < 16; m2 <<= 1) {
          p0 += __shfl_xor(p0, m2, 64);
          p1 += __shfl_xor(p1, m2, 64);
        }
        if (u_ep == 0) {
          float* dst = pp + (((s & 1) * 4 + mg) * 64 + row) * 128;
          cstf(dst + nblk,      p0);
          cstf(dst + 64 + nblk, p1);
        }
      }
    }

    // ---------------- grid barrier: flag array, no RMW, no cache flush ----------------
    __syncthreads();                          // drains vmcnt(0) in every wave: stores visible
    if (tid == 0) cst32(flg + bx, (unsigned int)(s + 1));
    if (tid < 64) {
      const u64* fp = (const u64*)flg;
      const unsigned int tgt = (unsigned int)(s + 1);
      int guard = 0;
      for (;;) {
        u64 a = cld64(fp + 2 * tid);
        u64 b = cld64(fp + 2 * tid + 1);
        unsigned int mn = umin4((unsigned int)a, (unsigned int)(a >> 32),
                                (unsigned int)b, (unsigned int)(b >> 32));
        if (__all(mn >= tgt)) break;
        if (++guard > 200000) break;          // bail-out: never hang the bench
        __builtin_amdgcn_s_sleep(1);
      }
    }
    asm volatile("" ::: "memory");
    __syncthreads();
  }
}

extern "C" void kernel_launch(void* const* d_in, const int* in_sizes, int n_in,
                              void* d_out, int out_size, void* d_ws, size_t ws_size,
                              hipStream_t stream) {
  const float* inp = (const float*)d_in[0];
  const float* Wx  = (const float*)d_in[1];
  const float* Wh  = (const float*)d_in[2];
  const float* b   = (const float*)d_in[3];
  const float* Wd  = (const float*)d_in[4];
  const float* bd  = (const float*)d_in[5];
  float* out = (float*)d_out;
  unsigned char* ws = (unsigned char*)d_ws;

  init_ws<<<1025, 256, 0, stream>>>((unsigned int*)ws);

  hipFuncSetAttribute((const void*)lstm_persist,
                      hipFuncAttributeMaxDynamicSharedMemorySize, LDS_BYTES);
  lstm_persist<<<256, 256, LDS_BYTES, stream>>>(inp, Wx, Wh, b, Wd, bd, out, ws);
}

// Round 6
// 2495.370 us; speedup vs baseline: 2.1411x; 2.1411x over previous
//
#include <hip/hip_runtime.h>

#define HH 1024
#define FOURH 4096
#define BB 256
#define TT 192
#define WARM 64
#define NSTEP 256        // 128 warm + 127 decode + 1 final-output-only iteration
#define UPB 16           // units per block
#define LDS_BYTES 152704

typedef _Float16 f16;
typedef _Float16 f16x8 __attribute__((ext_vector_type(8)));
typedef float    f32x4 __attribute__((ext_vector_type(4)));
typedef int      i32x4 __attribute__((ext_vector_type(4)));
typedef unsigned long long u64;

// workspace layout (bytes):
//   [0, 1 MiB)      : hx ping-pong, f16 [2][4 mg][64 kc][64 row][16 u]  (kc = unit>>4)
//   [1 MiB, +1 KiB) : per-block step flags (256 u32, monotonic = step+1)
//   [+1 KiB, +256K) : pred partials f32 [2][4 mg][64 nblk][64 row][2]   (block-contiguous)
#define HX_PING 524288
#define FLG_OFF 1048576
#define PP_OFF  (FLG_OFF + 1024)

__global__ void init_ws(unsigned int* ws) {
  int i = blockIdx.x * 256 + threadIdx.x;
  if (i < (FLG_OFF + 1024) / 4) ws[i] = 0u;
}

__device__ __forceinline__ float fsig(float x) { return 1.0f / (1.0f + __expf(-x)); }
__device__ __forceinline__ float ftanh(float x) {
  float ax = fabsf(x);
  float e  = __expf(-2.0f * ax);
  float t  = (1.0f - e) / (1.0f + e);
  return x < 0.0f ? -t : t;
}

// ---- agent-scope (device-coherent, L1/L2-bypassing) wide VMEM via asm ----
__device__ __forceinline__ i32x4 ald16(const void* p) {
  i32x4 v;
  asm volatile("global_load_dwordx4 %0, %1, off sc0 sc1" : "=v"(v) : "v"(p) : "memory");
  return v;
}
__device__ __forceinline__ void ast16(void* p, i32x4 v) {
  asm volatile("global_store_dwordx4 %0, %1, off sc0 sc1" :: "v"(p), "v"(v) : "memory");
}
__device__ __forceinline__ void vfence() { asm volatile("s_waitcnt vmcnt(0)" ::: "memory"); }
__device__ __forceinline__ void vwait16() { asm volatile("s_waitcnt vmcnt(16)" ::: "memory"); }
__device__ __forceinline__ i32x4 pass(i32x4 v) { asm volatile("" : "+v"(v)); return v; }

__device__ __forceinline__ void cst32(void* p, unsigned int v) {
  __hip_atomic_store((unsigned int*)p, v, __ATOMIC_RELAXED, __HIP_MEMORY_SCOPE_AGENT);
}
__device__ __forceinline__ void cstf(float* p, float v) {
  __hip_atomic_store(p, v, __ATOMIC_RELAXED, __HIP_MEMORY_SCOPE_AGENT);
}
__device__ __forceinline__ int imin4(int a, int b, int c, int d) {
  int x = a < b ? a : b;
  int y = c < d ? c : d;
  return x < y ? x : y;
}

__launch_bounds__(512, 1)
__global__ void lstm_persist(const float* __restrict__ inp,
                             const float* __restrict__ Wx,
                             const float* __restrict__ Wh,
                             const float* __restrict__ bias,
                             const float* __restrict__ Wd,
                             const float* __restrict__ bdp,
                             float* __restrict__ out,
                             unsigned char* __restrict__ ws)
{
  extern __shared__ char smem[];
  f16*   Wl     = (f16*)smem;                    // 131072 B, B-frag swizzled
  float* z_lds  = (float*)(smem + 131072);       // 64 x 68 fp32 = 17408 B
  float* x_sh   = z_lds + 64 * 68;               // 64 x 2
  float* mask_sh= x_sh + 128;                    // 64
  float* wx0_sh = mask_sh + 64;                  // 64
  float* wx1_sh = wx0_sh + 64;                   // 64
  float* b_sh   = wx1_sh + 64;                   // 64
  float* wd_sh  = b_sh + 64;                     // 32
  f16*   hsh    = (f16*)(wd_sh + 32);            // 64 row x 16 u f16 = 2048 B
  float* pps    = (float*)(hsh + 1024);          // 64 row x 2 f32 = 512 B

  const int tid  = threadIdx.x;
  const int bx   = blockIdx.x;
  const int mg   = bx >> 6;         // 4 batch groups of 64 rows
  const int nblk = bx & 63;         // 64 unit-groups of 16 units
  const int ublk = nblk * UPB;

  // ---------------- prologue: stage Wh slice into LDS in B-fragment order ----------------
  {
    const int wrow = tid >> 6;           // 0..7
    const int l    = tid & 63;
    const int gate = l >> 4;
    const int u    = l & 15;
    const int gcol = gate * HH + ublk + u;
    for (int rb = 0; rb < 128; rb += 8) {
      float v[8];
#pragma unroll
      for (int ii = 0; ii < 8; ++ii) {
        int r = (rb + ii) * 8 + wrow;
        v[ii] = Wh[r * FOURH + gcol];
      }
#pragma unroll
      for (int ii = 0; ii < 8; ++ii) {
        int r = (rb + ii) * 8 + wrow;
        int kk = r >> 5, sub = r & 31, q = sub >> 3, j = sub & 7;
        Wl[((kk * 4 + gate) * 64 + (q * 16 + u)) * 8 + j] = (f16)v[ii];
      }
    }
    if (tid < 64) {
      int g2 = tid >> 4, u2 = tid & 15;
      int gc = g2 * HH + ublk + u2;
      wx0_sh[tid] = Wx[gc];
      wx1_sh[tid] = Wx[FOURH + gc];
      b_sh[tid]   = bias[gc];
    }
    if (tid < UPB) {
      wd_sh[tid * 2 + 0] = Wd[(ublk + tid) * 2 + 0];
      wd_sh[tid * 2 + 1] = Wd[(ublk + tid) * 2 + 1];
    }
  }
  __syncthreads();

  // phase-C ownership: unit u_ep, rows r0 and r0+32
  const int u_ep = tid & 15;
  const int r0   = tid >> 4;           // 0..31
  float c_reg[2] = {0.f, 0.f};
  float h_reg[2] = {0.f, 0.f};

  const int wid  = tid >> 6;           // 0..7
  const int kh   = wid & 1;            // k-half: 512 k each
  const int mh   = wid >> 1;           // row-quarter: 16 rows each
  const int lane = tid & 63;
  const int lm   = lane & 15;
  const int lq   = lane >> 4;

  const float bd0 = bdp[0], bd1 = bdp[1];

  for (int s = 0; s < NSTEP; ++s) {
    const bool decode = (s >= 128);
    const int  ping   = s & 1;

    // ---------------- phase A-issue + A-prefetch ----------------
    i32x4 ppv[4];
    if (decode) {
      // packed pp reads: thread (u=u_ep, rp=r0) sums nblk = u + 16i for rows 2rp,2rp+1
      const char* pb = (const char*)ws + PP_OFF
                     + (size_t)((((s + 1) & 1) * 4 + mg) * 64) * 512 + r0 * 16;
#pragma unroll
      for (int i = 0; i < 4; ++i) ppv[i] = ald16(pb + (u_ep + 16 * i) * 512);
    } else {
      if (tid < 64) {
        int row = tid;
        const float* ip = inp + ((mg * 64 + row) * TT + (WARM + s)) * 2;
        float i0 = ip[0], i1 = ip[1];
        bool m = (i0 != -1.0f) || (i1 != -1.0f);
        x_sh[row * 2 + 0] = m ? i0 : 0.0f;
        x_sh[row * 2 + 1] = m ? i1 : 0.0f;
        mask_sh[row]      = m ? 1.0f : 0.0f;
      }
    }

    // A-fragments: wave (kh,mh) reads 16 rows x 512 k as 16 x 16B agent loads
    i32x4 q[16];
    {
      const char* abase = (const char*)ws + ping * HX_PING + mg * 131072
                        + (kh * 32 + (lq >> 1)) * 2048 + (16 * mh + lm) * 32 + (lq & 1) * 16;
#pragma unroll
      for (int ks = 0; ks < 16; ++ks) q[ks] = ald16(abase + ks * 4096);
    }

    // ---------------- phase A-complete: pred reduce (hides under A fill) ----------------
    if (decode) {
      vwait16();                     // 4 oldest (pp) done; 16 A-loads still in flight
      f32x4 v = __builtin_bit_cast(f32x4, pass(ppv[0]));
      v += __builtin_bit_cast(f32x4, pass(ppv[1]));
      v += __builtin_bit_cast(f32x4, pass(ppv[2]));
      v += __builtin_bit_cast(f32x4, pass(ppv[3]));
#pragma unroll
      for (int m2 = 1; m2 < 16; m2 <<= 1) {
        v.x += __shfl_xor(v.x, m2, 64);
        v.y += __shfl_xor(v.y, m2, 64);
        v.z += __shfl_xor(v.z, m2, 64);
        v.w += __shfl_xor(v.w, m2, 64);
      }
      if (u_ep == 0) {               // rows 2*r0, 2*r0+1, both outputs
        v.x += bd0; v.y += bd1; v.z += bd0; v.w += bd1;
        *(f32x4*)(x_sh + r0 * 4) = v;
        if (nblk == 0) {
          float* o = out + (size_t)((mg * 64 + 2 * r0) * 128 + (s - 128)) * 2;
          cstf(o, v.x); cstf(o + 1, v.y); cstf(o + 256, v.z); cstf(o + 257, v.w);
        }
      }
      if (s == NSTEP - 1) break;     // uniform across the whole grid
    }

    // ---------------- phase B: MFMA over this wave's (16 rows x 64 cols x 512 k) --------
    vfence();
    f32x4 acc[4];
#pragma unroll
    for (int n = 0; n < 4; ++n) acc[n] = f32x4{0.f, 0.f, 0.f, 0.f};
#pragma unroll
    for (int ks = 0; ks < 16; ++ks) {
      f16x8 a = __builtin_bit_cast(f16x8, pass(q[ks]));
      const f16* bb = Wl + (kh * 16 + ks) * 2048 + lane * 8;
      f16x8 b0 = *(const f16x8*)(bb);
      f16x8 b1 = *(const f16x8*)(bb + 512);
      f16x8 b2 = *(const f16x8*)(bb + 1024);
      f16x8 b3 = *(const f16x8*)(bb + 1536);
      acc[0] = __builtin_amdgcn_mfma_f32_16x16x32_f16(a, b0, acc[0], 0, 0, 0);
      acc[1] = __builtin_amdgcn_mfma_f32_16x16x32_f16(a, b1, acc[1], 0, 0, 0);
      acc[2] = __builtin_amdgcn_mfma_f32_16x16x32_f16(a, b2, acc[2], 0, 0, 0);
      acc[3] = __builtin_amdgcn_mfma_f32_16x16x32_f16(a, b3, acc[3], 0, 0, 0);
    }

    // ---------------- z merge: kh=0 store, barrier, kh=1 add ----------------
    {
      const int rb = 16 * mh + 4 * lq;   // C/D: row = 4*lq + reg (+16*mh), col = 16n+lm
      if (kh == 0) {
#pragma unroll
        for (int n = 0; n < 4; ++n)
#pragma unroll
          for (int r = 0; r < 4; ++r)
            z_lds[(rb + r) * 68 + 16 * n + lm] = acc[n][r];
      }
      __syncthreads();
      if (kh == 1) {
#pragma unroll
        for (int n = 0; n < 4; ++n)
#pragma unroll
          for (int r = 0; r < 4; ++r)
            z_lds[(rb + r) * 68 + 16 * n + lm] += acc[n][r];
      }
      __syncthreads();
    }

    // ---------------- phase C: gates + state update ----------------
    const bool wr_pred = (s >= 127);
#pragma unroll
    for (int q4 = 0; q4 < 2; ++q4) {
      int row = r0 + 32 * q4;
      float x0 = x_sh[row * 2], x1 = x_sh[row * 2 + 1];
      float* zr = z_lds + row * 68;
      float zi = zr[     u_ep] + x0 * wx0_sh[     u_ep] + x1 * wx1_sh[     u_ep] + b_sh[     u_ep];
      float zf = zr[16 + u_ep] + x0 * wx0_sh[16 + u_ep] + x1 * wx1_sh[16 + u_ep] + b_sh[16 + u_ep];
      float zg = zr[32 + u_ep] + x0 * wx0_sh[32 + u_ep] + x1 * wx1_sh[32 + u_ep] + b_sh[32 + u_ep];
      float zo = zr[48 + u_ep] + x0 * wx0_sh[48 + u_ep] + x1 * wx1_sh[48 + u_ep] + b_sh[48 + u_ep];
      float ig = fsig(zi), fg = fsig(zf), gg = ftanh(zg), og = fsig(zo);
      float cn = fg * c_reg[q4] + ig * gg;
      float hn = og * ftanh(cn);
      if (!decode) {
        bool m = mask_sh[row] > 0.5f;
        cn = m ? cn : c_reg[q4];
        hn = m ? hn : h_reg[q4];
      }
      c_reg[q4] = cn; h_reg[q4] = hn;

      hsh[row * 16 + u_ep] = (f16)hn;

      if (wr_pred) {
        float p0 = hn * wd_sh[u_ep * 2 + 0];
        float p1 = hn * wd_sh[u_ep * 2 + 1];
#pragma unroll
        for (int m2 = 1; m2 < 16; m2 <<= 1) {
          p0 += __shfl_xor(p0, m2, 64);
          p1 += __shfl_xor(p1, m2, 64);
        }
        if (u_ep == 0) { pps[row * 2] = p0; pps[row * 2 + 1] = p1; }
      }
    }
    __syncthreads();

    // ---------------- bounce: coalesced 16B agent stores of h (and pp) ----------------
    if (tid < 128) {
      f16x8 hv = *(const f16x8*)(hsh + tid * 8);   // row = tid>>1, u-octet = tid&1
      char* dst = (char*)ws + ((s + 1) & 1) * HX_PING + mg * 131072 + nblk * 2048 + tid * 16;
      ast16(dst, __builtin_bit_cast(i32x4, hv));
    }
    if (wr_pred && tid < 32) {
      f32x4 pv = *(const f32x4*)(pps + tid * 4);   // rows 2t, 2t+1
      char* dst = (char*)ws + PP_OFF + (size_t)(((ping)*4 + mg) * 64 + nblk) * 512 + tid * 16;
      ast16(dst, __builtin_bit_cast(i32x4, pv));
    }
    vfence();                                      // drain asm stores before flagging
    __syncthreads();

    // ---------------- grid barrier: flag array + wide agent-load poll ----------------
    if (tid == 0) cst32((unsigned int*)(ws + FLG_OFF) + bx, (unsigned int)(s + 1));
    if (tid < 64) {
      const char* fp = (const char*)ws + FLG_OFF + tid * 16;
      const int tgt = s + 1;
      int guard = 0;
      for (;;) {
        i32x4 f = ald16(fp);
        vfence();
        f = pass(f);
        int mn = imin4(f.x, f.y, f.z, f.w);
        if (__all(mn >= tgt)) break;
        if (++guard > 200000) break;               // bail-out: never hang the bench
        __builtin_amdgcn_s_sleep(1);
      }
    }
    __syncthreads();
  }
  vfence();
}

extern "C" void kernel_launch(void* const* d_in, const int* in_sizes, int n_in,
                              void* d_out, int out_size, void* d_ws, size_t ws_size,
                              hipStream_t stream) {
  const float* inp = (const float*)d_in[0];
  const float* Wx  = (const float*)d_in[1];
  const float* Wh  = (const float*)d_in[2];
  const float* b   = (const float*)d_in[3];
  const float* Wd  = (const float*)d_in[4];
  const float* bd  = (const float*)d_in[5];
  float* out = (float*)d_out;
  unsigned char* ws = (unsigned char*)d_ws;

  init_ws<<<1025, 256, 0, stream>>>((unsigned int*)ws);

  hipFuncSetAttribute((const void*)lstm_persist,
                      hipFuncAttributeMaxDynamicSharedMemorySize, LDS_BYTES);
  lstm_persist<<<256, 512, LDS_BYTES, stream>>>(inp, Wx, Wh, b, Wd, bd, out, ws);
}

// Round 7
// 2271.153 us; speedup vs baseline: 2.3525x; 1.0987x over previous
//
#include <hip/hip_runtime.h>

#define HH 1024
#define FOURH 4096
#define BB 256
#define TT 192
#define WARM 64
#define NSTEP 256        // 128 warm + 127 decode + 1 final-output-only iteration
#define UPB 16           // units per block
#define LDS_BYTES 152704

typedef _Float16 f16;
typedef _Float16 f16x8 __attribute__((ext_vector_type(8)));
typedef float    f32x4 __attribute__((ext_vector_type(4)));
typedef int      i32x4 __attribute__((ext_vector_type(4)));
typedef unsigned long long u64;

// workspace layout (bytes):
//   [0, 1 MiB)      : hx ping-pong, f16 [2][4 mg][64 kc][64 row][16 u]  (kc = unit>>4)
//   [1 MiB, +4 KiB) : per-mg step flags: u32 flg[4 mg][256] (only [0..63] used per mg)
//   [+4 KiB, +256K) : pred partials f32 [2][4 mg][64 nblk][64 row][2]   (block-contiguous)
#define HX_PING 524288
#define FLG_OFF 1048576
#define PP_OFF  (FLG_OFF + 4096)

__global__ void init_ws(unsigned int* ws) {
  int i = blockIdx.x * 256 + threadIdx.x;
  if (i < (FLG_OFF + 4096) / 4) ws[i] = 0u;
}

__device__ __forceinline__ float fsig(float x) { return 1.0f / (1.0f + __expf(-x)); }
__device__ __forceinline__ float ftanh(float x) {
  float ax = fabsf(x);
  float e  = __expf(-2.0f * ax);
  float t  = (1.0f - e) / (1.0f + e);
  return x < 0.0f ? -t : t;
}

// ---- agent-scope (device-coherent, L1/L2-bypassing) wide VMEM via asm ----
__device__ __forceinline__ i32x4 ald16(const void* p) {
  i32x4 v;
  asm volatile("global_load_dwordx4 %0, %1, off sc0 sc1" : "=v"(v) : "v"(p) : "memory");
  return v;
}
__device__ __forceinline__ void ast16(void* p, i32x4 v) {
  asm volatile("global_store_dwordx4 %0, %1, off sc0 sc1" :: "v"(p), "v"(v) : "memory");
}
#define VWAIT(n) asm volatile("s_waitcnt vmcnt(" #n ")" ::: "memory")
__device__ __forceinline__ void vfence() { asm volatile("s_waitcnt vmcnt(0)" ::: "memory"); }
__device__ __forceinline__ i32x4 pass(i32x4 v) { asm volatile("" : "+v"(v)); return v; }

__device__ __forceinline__ void cst32(void* p, unsigned int v) {
  __hip_atomic_store((unsigned int*)p, v, __ATOMIC_RELAXED, __HIP_MEMORY_SCOPE_AGENT);
}
__device__ __forceinline__ void cstf(float* p, float v) {
  __hip_atomic_store(p, v, __ATOMIC_RELAXED, __HIP_MEMORY_SCOPE_AGENT);
}
__device__ __forceinline__ int imin4(int a, int b, int c, int d) {
  int x = a < b ? a : b;
  int y = c < d ? c : d;
  return x < y ? x : y;
}

__launch_bounds__(512, 1)
__global__ void lstm_persist(const float* __restrict__ inp,
                             const float* __restrict__ Wx,
                             const float* __restrict__ Wh,
                             const float* __restrict__ bias,
                             const float* __restrict__ Wd,
                             const float* __restrict__ bdp,
                             float* __restrict__ out,
                             unsigned char* __restrict__ ws)
{
  extern __shared__ char smem[];
  f16*   Wl     = (f16*)smem;                    // 131072 B, B-frag swizzled
  float* z_lds  = (float*)(smem + 131072);       // 64 x 68 fp32 = 17408 B
  float* x_sh   = z_lds + 64 * 68;               // 64 x 2
  float* mask_sh= x_sh + 128;                    // 64
  float* wx0_sh = mask_sh + 64;                  // 64
  float* wx1_sh = wx0_sh + 64;                   // 64
  float* b_sh   = wx1_sh + 64;                   // 64
  float* wd_sh  = b_sh + 64;                     // 32
  f16*   hsh    = (f16*)(wd_sh + 32);            // 64 row x 16 u f16 = 2048 B
  float* pps    = (float*)(hsh + 1024);          // 64 row x 2 f32 = 512 B

  const int tid  = threadIdx.x;
  const int bx   = blockIdx.x;
  const int mg   = bx >> 6;         // 4 batch groups of 64 rows (independent LSTMs)
  const int nblk = bx & 63;         // 64 unit-groups of 16 units
  const int ublk = nblk * UPB;

  // ---------------- prologue: stage Wh slice into LDS in B-fragment order ----------------
  {
    const int wrow = tid >> 6;           // 0..7
    const int l    = tid & 63;
    const int gate = l >> 4;
    const int u    = l & 15;
    const int gcol = gate * HH + ublk + u;
    for (int rb = 0; rb < 128; rb += 8) {
      float v[8];
#pragma unroll
      for (int ii = 0; ii < 8; ++ii) {
        int r = (rb + ii) * 8 + wrow;
        v[ii] = Wh[r * FOURH + gcol];
      }
#pragma unroll
      for (int ii = 0; ii < 8; ++ii) {
        int r = (rb + ii) * 8 + wrow;
        int kk = r >> 5, sub = r & 31, q = sub >> 3, j = sub & 7;
        Wl[((kk * 4 + gate) * 64 + (q * 16 + u)) * 8 + j] = (f16)v[ii];
      }
    }
    if (tid < 64) {
      int g2 = tid >> 4, u2 = tid & 15;
      int gc = g2 * HH + ublk + u2;
      wx0_sh[tid] = Wx[gc];
      wx1_sh[tid] = Wx[FOURH + gc];
      b_sh[tid]   = bias[gc];
    }
    if (tid < UPB) {
      wd_sh[tid * 2 + 0] = Wd[(ublk + tid) * 2 + 0];
      wd_sh[tid * 2 + 1] = Wd[(ublk + tid) * 2 + 1];
    }
  }
  __syncthreads();

  // phase-C ownership: unit u_ep, rows r0 and r0+32
  const int u_ep = tid & 15;
  const int r0   = tid >> 4;           // 0..31
  float c_reg[2] = {0.f, 0.f};
  float h_reg[2] = {0.f, 0.f};

  const int wid  = tid >> 6;           // 0..7
  const int kh   = wid & 3;            // k-quarter: 256 k each
  const int mh   = wid >> 2;           // row-half: 32 rows each
  const int lane = tid & 63;
  const int lm   = lane & 15;
  const int lq   = lane >> 4;

  const float bd0 = bdp[0], bd1 = bdp[1];

  for (int s = 0; s < NSTEP; ++s) {
    const bool decode = (s >= 128);
    const int  ping   = s & 1;

    // ---------------- phase A-issue + A-prefetch ----------------
    i32x4 ppv[4];
    if (decode) {
      // packed pp reads: thread (u=u_ep, rp=r0) sums nblk = u + 16i for rows 2rp,2rp+1
      const char* pb = (const char*)ws + PP_OFF
                     + (size_t)((((s + 1) & 1) * 4 + mg) * 64) * 512 + r0 * 16;
#pragma unroll
      for (int i = 0; i < 4; ++i) ppv[i] = ald16(pb + (u_ep + 16 * i) * 512);
    } else {
      if (tid < 64) {
        int row = tid;
        const float* ip = inp + ((mg * 64 + row) * TT + (WARM + s)) * 2;
        float i0 = ip[0], i1 = ip[1];
        bool m = (i0 != -1.0f) || (i1 != -1.0f);
        x_sh[row * 2 + 0] = m ? i0 : 0.0f;
        x_sh[row * 2 + 1] = m ? i1 : 0.0f;
        mask_sh[row]      = m ? 1.0f : 0.0f;
      }
    }

    // A-fragments: wave (kh,mh) = rows 32*mh..+32, k in [256*kh, 256*kh+256)
    // issue order q[0..15] = ks-major, rg (16-row group) minor
    i32x4 q[16];
    {
      const char* ab0 = (const char*)ws + ping * HX_PING + mg * 131072
                      + (kh * 16 + (lq >> 1)) * 2048 + (32 * mh + lm) * 32 + (lq & 1) * 16;
      const char* ab1 = ab0 + 16 * 32;
#pragma unroll
      for (int ks = 0; ks < 8; ++ks) {
        q[ks * 2 + 0] = ald16(ab0 + ks * 4096);
        q[ks * 2 + 1] = ald16(ab1 + ks * 4096);
      }
    }

    // ---------------- phase A-complete: pred reduce (hides under A fill) ----------------
    if (decode) {
      VWAIT(16);                     // 4 oldest (pp) done; 16 A-loads still in flight
      f32x4 v = __builtin_bit_cast(f32x4, pass(ppv[0]));
      v += __builtin_bit_cast(f32x4, pass(ppv[1]));
      v += __builtin_bit_cast(f32x4, pass(ppv[2]));
      v += __builtin_bit_cast(f32x4, pass(ppv[3]));
#pragma unroll
      for (int m2 = 1; m2 < 16; m2 <<= 1) {
        v.x += __shfl_xor(v.x, m2, 64);
        v.y += __shfl_xor(v.y, m2, 64);
        v.z += __shfl_xor(v.z, m2, 64);
        v.w += __shfl_xor(v.w, m2, 64);
      }
      if (u_ep == 0) {               // rows 2*r0, 2*r0+1, both outputs
        v.x += bd0; v.y += bd1; v.z += bd0; v.w += bd1;
        *(f32x4*)(x_sh + r0 * 4) = v;
        if (nblk == 0) {
          float* o = out + (size_t)((mg * 64 + 2 * r0) * 128 + (s - 128)) * 2;
          cstf(o, v.x); cstf(o + 1, v.y); cstf(o + 256, v.z); cstf(o + 257, v.w);
        }
      }
      if (s == NSTEP - 1) break;     // uniform across the whole grid
    }

    // ---------------- phase B: MFMA, graded vmcnt (compute ks0-3 while ks4-7 fill) -----
    f32x4 acc[2][4];
#pragma unroll
    for (int m = 0; m < 2; ++m)
#pragma unroll
      for (int n = 0; n < 4; ++n) acc[m][n] = f32x4{0.f, 0.f, 0.f, 0.f};

    VWAIT(8);                        // q[0..7] (ks 0..3) resident
#pragma unroll
    for (int ks = 0; ks < 4; ++ks) {
      const f16* bb = Wl + (kh * 8 + ks) * 2048 + lane * 8;
      f16x8 b0 = *(const f16x8*)(bb);
      f16x8 b1 = *(const f16x8*)(bb + 512);
      f16x8 b2 = *(const f16x8*)(bb + 1024);
      f16x8 b3 = *(const f16x8*)(bb + 1536);
#pragma unroll
      for (int m = 0; m < 2; ++m) {
        f16x8 a = __builtin_bit_cast(f16x8, pass(q[ks * 2 + m]));
        acc[m][0] = __builtin_amdgcn_mfma_f32_16x16x32_f16(a, b0, acc[m][0], 0, 0, 0);
        acc[m][1] = __builtin_amdgcn_mfma_f32_16x16x32_f16(a, b1, acc[m][1], 0, 0, 0);
        acc[m][2] = __builtin_amdgcn_mfma_f32_16x16x32_f16(a, b2, acc[m][2], 0, 0, 0);
        acc[m][3] = __builtin_amdgcn_mfma_f32_16x16x32_f16(a, b3, acc[m][3], 0, 0, 0);
      }
    }
    VWAIT(0);                        // q[8..15] resident
#pragma unroll
    for (int ks = 4; ks < 8; ++ks) {
      const f16* bb = Wl + (kh * 8 + ks) * 2048 + lane * 8;
      f16x8 b0 = *(const f16x8*)(bb);
      f16x8 b1 = *(const f16x8*)(bb + 512);
      f16x8 b2 = *(const f16x8*)(bb + 1024);
      f16x8 b3 = *(const f16x8*)(bb + 1536);
#pragma unroll
      for (int m = 0; m < 2; ++m) {
        f16x8 a = __builtin_bit_cast(f16x8, pass(q[ks * 2 + m]));
        acc[m][0] = __builtin_amdgcn_mfma_f32_16x16x32_f16(a, b0, acc[m][0], 0, 0, 0);
        acc[m][1] = __builtin_amdgcn_mfma_f32_16x16x32_f16(a, b1, acc[m][1], 0, 0, 0);
        acc[m][2] = __builtin_amdgcn_mfma_f32_16x16x32_f16(a, b2, acc[m][2], 0, 0, 0);
        acc[m][3] = __builtin_amdgcn_mfma_f32_16x16x32_f16(a, b3, acc[m][3], 0, 0, 0);
      }
    }

    // ---------------- z merge: 4 sequential k-quarter stages (race-free by rows) --------
    // C/D layout: row = 32*mh + 16*m + 4*lq + reg, col = 16*n + lm
#pragma unroll
    for (int stage = 0; stage < 4; ++stage) {
      if (kh == stage) {
#pragma unroll
        for (int m = 0; m < 2; ++m) {
          const int rb = 32 * mh + 16 * m + 4 * lq;
#pragma unroll
          for (int n = 0; n < 4; ++n) {
#pragma unroll
            for (int r = 0; r < 4; ++r) {
              float* zp = &z_lds[(rb + r) * 68 + 16 * n + lm];
              if (stage == 0) *zp = acc[m][n][r];
              else            *zp += acc[m][n][r];
            }
          }
        }
      }
      __syncthreads();
    }

    // ---------------- phase C: gates + state update ----------------
    const bool wr_pred = (s >= 127);
#pragma unroll
    for (int q4 = 0; q4 < 2; ++q4) {
      int row = r0 + 32 * q4;
      float x0 = x_sh[row * 2], x1 = x_sh[row * 2 + 1];
      float* zr = z_lds + row * 68;
      float zi = zr[     u_ep] + x0 * wx0_sh[     u_ep] + x1 * wx1_sh[     u_ep] + b_sh[     u_ep];
      float zf = zr[16 + u_ep] + x0 * wx0_sh[16 + u_ep] + x1 * wx1_sh[16 + u_ep] + b_sh[16 + u_ep];
      float zg = zr[32 + u_ep] + x0 * wx0_sh[32 + u_ep] + x1 * wx1_sh[32 + u_ep] + b_sh[32 + u_ep];
      float zo = zr[48 + u_ep] + x0 * wx0_sh[48 + u_ep] + x1 * wx1_sh[48 + u_ep] + b_sh[48 + u_ep];
      float ig = fsig(zi), fg = fsig(zf), gg = ftanh(zg), og = fsig(zo);
      float cn = fg * c_reg[q4] + ig * gg;
      float hn = og * ftanh(cn);
      if (!decode) {
        bool m = mask_sh[row] > 0.5f;
        cn = m ? cn : c_reg[q4];
        hn = m ? hn : h_reg[q4];
      }
      c_reg[q4] = cn; h_reg[q4] = hn;

      hsh[row * 16 + u_ep] = (f16)hn;

      if (wr_pred) {
        float p0 = hn * wd_sh[u_ep * 2 + 0];
        float p1 = hn * wd_sh[u_ep * 2 + 1];
#pragma unroll
        for (int m2 = 1; m2 < 16; m2 <<= 1) {
          p0 += __shfl_xor(p0, m2, 64);
          p1 += __shfl_xor(p1, m2, 64);
        }
        if (u_ep == 0) { pps[row * 2] = p0; pps[row * 2 + 1] = p1; }
      }
    }
    __syncthreads();

    // ---------------- bounce: coalesced 16B agent stores of h (and pp) ----------------
    if (tid < 128) {
      f16x8 hv = *(const f16x8*)(hsh + tid * 8);   // row = tid>>1, u-octet = tid&1
      char* dst = (char*)ws + ((s + 1) & 1) * HX_PING + mg * 131072 + nblk * 2048 + tid * 16;
      ast16(dst, __builtin_bit_cast(i32x4, hv));
    }
    if (wr_pred && tid < 32) {
      f32x4 pv = *(const f32x4*)(pps + tid * 4);   // rows 2t, 2t+1
      char* dst = (char*)ws + PP_OFF + (size_t)(((ping)*4 + mg) * 64 + nblk) * 512 + tid * 16;
      ast16(dst, __builtin_bit_cast(i32x4, pv));
    }
    vfence();                                      // drain asm stores before flagging
    __syncthreads();

    // ---------------- per-mg barrier: 64 flags, wide agent-load poll ----------------
    {
      unsigned int* fl = (unsigned int*)((char*)ws + FLG_OFF + mg * 1024);
      if (tid == 0) cst32(fl + nblk, (unsigned int)(s + 1));
      if (tid < 16) {
        const char* fp = (const char*)fl + tid * 16;
        const int tgt = s + 1;
        int guard = 0;
        for (;;) {
          i32x4 f = ald16(fp);
          vfence();
          f = pass(f);
          int mn = imin4(f.x, f.y, f.z, f.w);
          if (__all(mn >= tgt)) break;
          if (++guard > 200000) break;             // bail-out: never hang the bench
          __builtin_amdgcn_s_sleep(1);
        }
      }
      __syncthreads();
    }
  }
  vfence();
}

extern "C" void kernel_launch(void* const* d_in, const int* in_sizes, int n_in,
                              void* d_out, int out_size, void* d_ws, size_t ws_size,
                              hipStream_t stream) {
  const float* inp = (const float*)d_in[0];
  const float* Wx  = (const float*)d_in[1];
  const float* Wh  = (const float*)d_in[2];
  const float* b   = (const float*)d_in[3];
  const float* Wd  = (const float*)d_in[4];
  const float* bd  = (const float*)d_in[5];
  float* out = (float*)d_out;
  unsigned char* ws = (unsigned char*)d_ws;

  init_ws<<<1030, 256, 0, stream>>>((unsigned int*)ws);

  hipFuncSetAttribute((const void*)lstm_persist,
                      hipFuncAttributeMaxDynamicSharedMemorySize, LDS_BYTES);
  lstm_persist<<<256, 512, LDS_BYTES, stream>>>(inp, Wx, Wh, b, Wd, bd, out, ws);
}

// Round 11
// 2212.964 us; speedup vs baseline: 2.4144x; 1.0263x over previous
//
#include <hip/hip_runtime.h>

#define HH 1024
#define FOURH 4096
#define BB 256
#define TT 192
#define WARM 64
#define NSTEP 256        // 128 warm + 127 decode + 1 final-output-only iteration
#define UPB 16           // units per block
#define LDS_BYTES 152704

typedef _Float16 f16;
typedef _Float16 f16x8 __attribute__((ext_vector_type(8)));
typedef float    f32x4 __attribute__((ext_vector_type(4)));
typedef int      i32x4 __attribute__((ext_vector_type(4)));

// workspace layout (bytes):
//   [0, 4 MiB)       : hx 8-slot ring, f16 [8 slot][4 mg][64 kc][64 row][16 u]
//   [4 MiB, +4 KiB)  : per-mg step flags: u32 flg[4 mg][256] (only [0..63] used per mg)
//   [+4 KiB, +256 K) : pred partials f32 [2][4 mg][64 nblk][64 row][2] (block-contiguous)
#define HX_SLOT 524288
#define FLG_OFF 4194304
#define PP_OFF  (FLG_OFF + 4096)

__global__ void init_ws(unsigned int* ws) {
  int i = blockIdx.x * 256 + threadIdx.x;
  if (i < 131072) ws[i] = 0u;                              // hx slot 0 = initial h = 0
  else if (i < 132096) ws[FLG_OFF / 4 + (i - 131072)] = 0u; // flags
}

__device__ __forceinline__ float fsig(float x) { return 1.0f / (1.0f + __expf(-x)); }
__device__ __forceinline__ float ftanh(float x) {
  float ax = fabsf(x);
  float e  = __expf(-2.0f * ax);
  float t  = (1.0f - e) / (1.0f + e);
  return x < 0.0f ? -t : t;
}

// ---- agent-scope (device-coherent, cache-bypassing) wide VMEM via asm ----
__device__ __forceinline__ i32x4 ald16(const void* p) {
  i32x4 v;
  asm volatile("global_load_dwordx4 %0, %1, off sc0 sc1" : "=v"(v) : "v"(p) : "memory");
  return v;
}
__device__ __forceinline__ void ast16(void* p, i32x4 v) {
  asm volatile("global_store_dwordx4 %0, %1, off sc0 sc1" :: "v"(p), "v"(v) : "memory");
}
// ---- plain cached 16B load: coherence via 8-slot ring + buffer_inv every 8 steps.
// Safe because ALL kernel global writes are write-through (sc0 sc1): L3 is always
// authoritative, L2 re-population is always fresh, and each slot sees exactly one
// self-inv between consecutive reads (slot X read only at steps ≡ X mod 8).
__device__ __forceinline__ i32x4 cld16(const void* p) {
  i32x4 v;
  asm volatile("global_load_dwordx4 %0, %1, off" : "=v"(v) : "v"(p) : "memory");
  return v;
}
#define VWAIT(n) asm volatile("s_waitcnt vmcnt(" #n ")" ::: "memory")
__device__ __forceinline__ void vfence() { asm volatile("s_waitcnt vmcnt(0)" ::: "memory"); }
__device__ __forceinline__ i32x4 pass(i32x4 v) { asm volatile("" : "+v"(v)); return v; }

__device__ __forceinline__ void cst32(void* p, unsigned int v) {
  __hip_atomic_store((unsigned int*)p, v, __ATOMIC_RELAXED, __HIP_MEMORY_SCOPE_AGENT);
}
__device__ __forceinline__ void cstf(float* p, float v) {
  __hip_atomic_store(p, v, __ATOMIC_RELAXED, __HIP_MEMORY_SCOPE_AGENT);
}
__device__ __forceinline__ int imin4(int a, int b, int c, int d) {
  int x = a < b ? a : b;
  int y = c < d ? c : d;
  return x < y ? x : y;
}

__launch_bounds__(512, 1)
__global__ void lstm_persist(const float* __restrict__ inp,
                             const float* __restrict__ Wx,
                             const float* __restrict__ Wh,
                             const float* __restrict__ bias,
                             const float* __restrict__ Wd,
                             const float* __restrict__ bdp,
                             float* __restrict__ out,
                             unsigned char* __restrict__ ws)
{
  extern __shared__ char smem[];
  f16*   Wl     = (f16*)smem;                    // 131072 B, B-frag swizzled
  float* z_lds  = (float*)(smem + 131072);       // 64 x 68 fp32 = 17408 B
  float* x_sh   = z_lds + 64 * 68;               // 64 x 2
  float* mask_sh= x_sh + 128;                    // 64
  float* wx0_sh = mask_sh + 64;                  // 64
  float* wx1_sh = wx0_sh + 64;                   // 64
  float* b_sh   = wx1_sh + 64;                   // 64
  float* wd_sh  = b_sh + 64;                     // 32
  f16*   hsh    = (f16*)(wd_sh + 32);            // 64 row x 16 u f16 = 2048 B
  float* pps    = (float*)(hsh + 1024);          // 64 row x 2 f32 = 512 B

  const int tid  = threadIdx.x;
  const int bx   = blockIdx.x;
  const int mg   = bx >> 6;         // 4 batch groups of 64 rows (independent LSTMs)
  const int nblk = bx & 63;         // 64 unit-groups of 16 units
  const int ublk = nblk * UPB;

  // ---------------- prologue: stage Wh slice into LDS in B-fragment order ----------------
  {
    const int wrow = tid >> 6;           // 0..7
    const int l    = tid & 63;
    const int gate = l >> 4;
    const int u    = l & 15;
    const int gcol = gate * HH + ublk + u;
    for (int rb = 0; rb < 128; rb += 8) {
      float v[8];
#pragma unroll
      for (int ii = 0; ii < 8; ++ii) {
        int r = (rb + ii) * 8 + wrow;
        v[ii] = Wh[r * FOURH + gcol];
      }
#pragma unroll
      for (int ii = 0; ii < 8; ++ii) {
        int r = (rb + ii) * 8 + wrow;
        int kk = r >> 5, sub = r & 31, q = sub >> 3, j = sub & 7;
        Wl[((kk * 4 + gate) * 64 + (q * 16 + u)) * 8 + j] = (f16)v[ii];
      }
    }
    if (tid < 64) {
      int g2 = tid >> 4, u2 = tid & 15;
      int gc = g2 * HH + ublk + u2;
      wx0_sh[tid] = Wx[gc];
      wx1_sh[tid] = Wx[FOURH + gc];
      b_sh[tid]   = bias[gc];
    }
    if (tid < UPB) {
      wd_sh[tid * 2 + 0] = Wd[(ublk + tid) * 2 + 0];
      wd_sh[tid * 2 + 1] = Wd[(ublk + tid) * 2 + 1];
    }
  }
  __syncthreads();

  // phase-C ownership: unit u_ep, rows r0 and r0+32
  const int u_ep = tid & 15;
  const int r0   = tid >> 4;           // 0..31
  float c_reg[2] = {0.f, 0.f};
  float h_reg[2] = {0.f, 0.f};

  const int wid  = tid >> 6;           // 0..7
  const int kh   = wid & 3;            // k-quarter: 256 k each
  const int mh   = wid >> 2;           // row-half: 32 rows each
  const int lane = tid & 63;
  const int lm   = lane & 15;
  const int lq   = lane >> 4;

  const float bd0 = bdp[0], bd1 = bdp[1];

  for (int s = 0; s < NSTEP; ++s) {
    const bool decode = (s >= 128);

    // ---- coherence epoch: every 8 steps drop (clean) L1 + this XCD's L2 lines.
    // Write-through global stores mean no dirty data can be lost.
    if ((s & 7) == 0) {
      if (wid == 0) {
        asm volatile("buffer_inv sc1" ::: "memory");
        vfence();
      }
      __syncthreads();
    }

    // ---------------- phase A-issue: pred-partial loads (decode, all 512 threads) -------
    i32x4 ppv[4];
    const int prow = tid >> 4;           // == r0; via pp thread mapping below
    if (decode) {
      // packed pp reads: thread (u=u_ep, rp=r0) sums nblk = u_ep + 16i for rows 2r0, 2r0+1
      const char* pb = (const char*)ws + PP_OFF
                     + (size_t)((((s + 1) & 1) * 4 + mg) * 64) * 512 + r0 * 16;
#pragma unroll
      for (int i = 0; i < 4; ++i) ppv[i] = ald16(pb + (u_ep + 16 * i) * 512);
    } else {
      if (tid < 64) {
        int row = tid;
        const float* ip = inp + ((mg * 64 + row) * TT + (WARM + s)) * 2;
        float i0 = ip[0], i1 = ip[1];
        bool m = (i0 != -1.0f) || (i1 != -1.0f);
        x_sh[row * 2 + 0] = m ? i0 : 0.0f;
        x_sh[row * 2 + 1] = m ? i1 : 0.0f;
        mask_sh[row]      = m ? 1.0f : 0.0f;
      }
    }

    // ---------------- A-fragments: cached 16B loads from ring slot s&7 ----------------
    // wave (kh,mh) = rows 32*mh..+32, k in [256*kh, 256*kh+256)
    i32x4 q[16];
    {
      const char* ab0 = (const char*)ws + (s & 7) * HX_SLOT + mg * 131072
                      + (kh * 16 + (lq >> 1)) * 2048 + (32 * mh + lm) * 32 + (lq & 1) * 16;
      const char* ab1 = ab0 + 16 * 32;
#pragma unroll
      for (int ks = 0; ks < 8; ++ks) {
        q[ks * 2 + 0] = cld16(ab0 + ks * 4096);
        q[ks * 2 + 1] = cld16(ab1 + ks * 4096);
      }
    }

    // ---------------- phase A-complete: pred reduce (hides under A fill) ----------------
    if (decode) {
      VWAIT(16);                     // 4 oldest (pp) done; 16 A-loads still in flight
      f32x4 v = __builtin_bit_cast(f32x4, pass(ppv[0]));
      v += __builtin_bit_cast(f32x4, pass(ppv[1]));
      v += __builtin_bit_cast(f32x4, pass(ppv[2]));
      v += __builtin_bit_cast(f32x4, pass(ppv[3]));
#pragma unroll
      for (int m2 = 1; m2 < 16; m2 <<= 1) {
        v.x += __shfl_xor(v.x, m2, 64);
        v.y += __shfl_xor(v.y, m2, 64);
        v.z += __shfl_xor(v.z, m2, 64);
        v.w += __shfl_xor(v.w, m2, 64);
      }
      if (u_ep == 0) {               // rows 2*r0, 2*r0+1, both outputs
        v.x += bd0; v.y += bd1; v.z += bd0; v.w += bd1;
        *(f32x4*)(x_sh + r0 * 4) = v;
        if (nblk == 0) {
          float* o = out + (size_t)((mg * 64 + 2 * r0) * 128 + (s - 128)) * 2;
          cstf(o, v.x); cstf(o + 1, v.y); cstf(o + 256, v.z); cstf(o + 257, v.w);
        }
      }
      if (s == NSTEP - 1) break;     // uniform across the whole grid
    }

    // ---------------- phase B: MFMA, graded vmcnt (compute ks0-3 while ks4-7 fill) -----
    f32x4 acc[2][4];
#pragma unroll
    for (int m = 0; m < 2; ++m)
#pragma unroll
      for (int n = 0; n < 4; ++n) acc[m][n] = f32x4{0.f, 0.f, 0.f, 0.f};

    VWAIT(8);                        // q[0..7] (ks 0..3) resident
#pragma unroll
    for (int ks = 0; ks < 4; ++ks) {
      const f16* bb = Wl + (kh * 8 + ks) * 2048 + lane * 8;
      f16x8 b0 = *(const f16x8*)(bb);
      f16x8 b1 = *(const f16x8*)(bb + 512);
      f16x8 b2 = *(const f16x8*)(bb + 1024);
      f16x8 b3 = *(const f16x8*)(bb + 1536);
#pragma unroll
      for (int m = 0; m < 2; ++m) {
        f16x8 a = __builtin_bit_cast(f16x8, pass(q[ks * 2 + m]));
        acc[m][0] = __builtin_amdgcn_mfma_f32_16x16x32_f16(a, b0, acc[m][0], 0, 0, 0);
        acc[m][1] = __builtin_amdgcn_mfma_f32_16x16x32_f16(a, b1, acc[m][1], 0, 0, 0);
        acc[m][2] = __builtin_amdgcn_mfma_f32_16x16x32_f16(a, b2, acc[m][2], 0, 0, 0);
        acc[m][3] = __builtin_amdgcn_mfma_f32_16x16x32_f16(a, b3, acc[m][3], 0, 0, 0);
      }
    }
    VWAIT(0);                        // q[8..15] resident
#pragma unroll
    for (int ks = 4; ks < 8; ++ks) {
      const f16* bb = Wl + (kh * 8 + ks) * 2048 + lane * 8;
      f16x8 b0 = *(const f16x8*)(bb);
      f16x8 b1 = *(const f16x8*)(bb + 512);
      f16x8 b2 = *(const f16x8*)(bb + 1024);
      f16x8 b3 = *(const f16x8*)(bb + 1536);
#pragma unroll
      for (int m = 0; m < 2; ++m) {
        f16x8 a = __builtin_bit_cast(f16x8, pass(q[ks * 2 + m]));
        acc[m][0] = __builtin_amdgcn_mfma_f32_16x16x32_f16(a, b0, acc[m][0], 0, 0, 0);
        acc[m][1] = __builtin_amdgcn_mfma_f32_16x16x32_f16(a, b1, acc[m][1], 0, 0, 0);
        acc[m][2] = __builtin_amdgcn_mfma_f32_16x16x32_f16(a, b2, acc[m][2], 0, 0, 0);
        acc[m][3] = __builtin_amdgcn_mfma_f32_16x16x32_f16(a, b3, acc[m][3], 0, 0, 0);
      }
    }

    // ---------------- z merge: 4 sequential k-quarter stages (race-free by rows) --------
    // C/D layout: row = 32*mh + 16*m + 4*lq + reg, col = 16*n + lm
#pragma unroll
    for (int stage = 0; stage < 4; ++stage) {
      if (kh == stage) {
#pragma unroll
        for (int m = 0; m < 2; ++m) {
          const int rb = 32 * mh + 16 * m + 4 * lq;
#pragma unroll
          for (int n = 0; n < 4; ++n) {
#pragma unroll
            for (int r = 0; r < 4; ++r) {
              float* zp = &z_lds[(rb + r) * 68 + 16 * n + lm];
              if (stage == 0) *zp = acc[m][n][r];
              else            *zp += acc[m][n][r];
            }
          }
        }
      }
      __syncthreads();
    }

    // ---------------- phase C: gates + state update ----------------
    const bool wr_pred = (s >= 127);
#pragma unroll
    for (int q4 = 0; q4 < 2; ++q4) {
      int row = r0 + 32 * q4;
      float x0 = x_sh[row * 2], x1 = x_sh[row * 2 + 1];
      float* zr = z_lds + row * 68;
      float zi = zr[     u_ep] + x0 * wx0_sh[     u_ep] + x1 * wx1_sh[     u_ep] + b_sh[     u_ep];
      float zf = zr[16 + u_ep] + x0 * wx0_sh[16 + u_ep] + x1 * wx1_sh[16 + u_ep] + b_sh[16 + u_ep];
      float zg = zr[32 + u_ep] + x0 * wx0_sh[32 + u_ep] + x1 * wx1_sh[32 + u_ep] + b_sh[32 + u_ep];
      float zo = zr[48 + u_ep] + x0 * wx0_sh[48 + u_ep] + x1 * wx1_sh[48 + u_ep] + b_sh[48 + u_ep];
      float ig = fsig(zi), fg = fsig(zf), gg = ftanh(zg), og = fsig(zo);
      float cn = fg * c_reg[q4] + ig * gg;
      float hn = og * ftanh(cn);
      if (!decode) {
        bool m = mask_sh[row] > 0.5f;
        cn = m ? cn : c_reg[q4];
        hn = m ? hn : h_reg[q4];
      }
      c_reg[q4] = cn; h_reg[q4] = hn;

      hsh[row * 16 + u_ep] = (f16)hn;

      if (wr_pred) {
        float p0 = hn * wd_sh[u_ep * 2 + 0];
        float p1 = hn * wd_sh[u_ep * 2 + 1];
#pragma unroll
        for (int m2 = 1; m2 < 16; m2 <<= 1) {
          p0 += __shfl_xor(p0, m2, 64);
          p1 += __shfl_xor(p1, m2, 64);
        }
        if (u_ep == 0) { pps[row * 2] = p0; pps[row * 2 + 1] = p1; }
      }
    }
    __syncthreads();

    // ---------------- bounce: coalesced 16B write-through stores of h (and pp) ----------
    if (tid < 128) {
      f16x8 hv = *(const f16x8*)(hsh + tid * 8);   // row = tid>>1, u-octet = tid&1
      char* dst = (char*)ws + ((s + 1) & 7) * HX_SLOT + mg * 131072 + nblk * 2048 + tid * 16;
      ast16(dst, __builtin_bit_cast(i32x4, hv));
    }
    if (wr_pred && tid < 32) {
      f32x4 pv = *(const f32x4*)(pps + tid * 4);   // rows 2t, 2t+1
      char* dst = (char*)ws + PP_OFF + (size_t)(((s & 1) * 4 + mg) * 64 + nblk) * 512 + tid * 16;
      ast16(dst, __builtin_bit_cast(i32x4, pv));
    }
    vfence();                                      // drain asm stores before flagging
    __syncthreads();

    // ---------------- per-mg barrier: 64 flags, wide agent-load poll ----------------
    {
      unsigned int* fl = (unsigned int*)((char*)ws + FLG_OFF + mg * 1024);
      if (tid == 0) cst32(fl + nblk, (unsigned int)(s + 1));
      if (tid < 16) {
        const char* fp = (const char*)fl + tid * 16;
        const int tgt = s + 1;
        int guard = 0;
        for (;;) {
          i32x4 f = ald16(fp);
          vfence();
          f = pass(f);
          int mn = imin4(f.x, f.y, f.z, f.w);
          if (__all(mn >= tgt)) break;
          if (++guard > 200000) break;             // bail-out: never hang the bench
          __builtin_amdgcn_s_sleep(1);
        }
      }
      __syncthreads();
    }
  }
  vfence();
}

extern "C" void kernel_launch(void* const* d_in, const int* in_sizes, int n_in,
                              void* d_out, int out_size, void* d_ws, size_t ws_size,
                              hipStream_t stream) {
  const float* inp = (const float*)d_in[0];
  const float* Wx  = (const float*)d_in[1];
  const float* Wh  = (const float*)d_in[2];
  const float* b   = (const float*)d_in[3];
  const float* Wd  = (const float*)d_in[4];
  const float* bd  = (const float*)d_in[5];
  float* out = (float*)d_out;
  unsigned char* ws = (unsigned char*)d_ws;

  init_ws<<<517, 256, 0, stream>>>((unsigned int*)ws);

  hipFuncSetAttribute((const void*)lstm_persist,
                      hipFuncAttributeMaxDynamicSharedMemorySize, LDS_BYTES);
  lstm_persist<<<256, 512, LDS_BYTES, stream>>>(inp, Wx, Wh, b, Wd, bd, out, ws);
}

// Round 12
// 2177.933 us; speedup vs baseline: 2.4532x; 1.0161x over previous
//
#include <hip/hip_runtime.h>

#define HH 1024
#define FOURH 4096
#define BB 256
#define TT 192
#define WARM 64
#define NSTEP 256        // 128 warm + 127 decode + 1 final-output-only iteration
#define UPB 16           // units per block
#define LDS_BYTES 152704

typedef _Float16 f16;
typedef _Float16 f16x8 __attribute__((ext_vector_type(8)));
typedef float    f32x4 __attribute__((ext_vector_type(4)));
typedef int      i32x4 __attribute__((ext_vector_type(4)));

// workspace layout (bytes):
//   [0, 4 MiB)       : hx 8-slot ring, f16 [8 slot][4 mg][64 kc][64 row][16 u]
//   [4 MiB, +4 KiB)  : per-mg step flags: u32 flg[4 mg][256] (only [0..63] used per mg)
//   [+4 KiB, +1 MiB) : pred partials, 8-slot ring: f32 [8 slot][4 mg][64 nblk][64 row][2]
#define HX_SLOT 524288
#define FLG_OFF 4194304
#define PP_OFF  (FLG_OFF + 4096)

__global__ void init_ws(unsigned int* ws) {
  int i = blockIdx.x * 256 + threadIdx.x;
  if (i < 131072) ws[i] = 0u;                               // hx slot 0 = initial h = 0
  else if (i < 132096) ws[FLG_OFF / 4 + (i - 131072)] = 0u; // flags
}

__device__ __forceinline__ float fsig(float x) { return 1.0f / (1.0f + __expf(-x)); }
__device__ __forceinline__ float ftanh(float x) {
  float ax = fabsf(x);
  float e  = __expf(-2.0f * ax);
  float t  = (1.0f - e) / (1.0f + e);
  return x < 0.0f ? -t : t;
}

// ---- agent-scope (device-coherent, cache-bypassing) wide VMEM via asm ----
__device__ __forceinline__ i32x4 ald16(const void* p) {
  i32x4 v;
  asm volatile("global_load_dwordx4 %0, %1, off sc0 sc1" : "=v"(v) : "v"(p) : "memory");
  return v;
}
__device__ __forceinline__ void ast16(void* p, i32x4 v) {
  asm volatile("global_store_dwordx4 %0, %1, off sc0 sc1" :: "v"(p), "v"(v) : "memory");
}
// ---- plain cached 16B load: coherence via 8-slot rings + buffer_inv every 8 steps.
// Safe because ALL kernel global writes are write-through (sc0 sc1): L3 is always
// authoritative, L2 re-population is always fresh, and each ring slot sees exactly one
// self-inv between consecutive reads (slot X read only at one step-residue mod 8).
__device__ __forceinline__ i32x4 cld16(const void* p) {
  i32x4 v;
  asm volatile("global_load_dwordx4 %0, %1, off" : "=v"(v) : "v"(p) : "memory");
  return v;
}
#define VWAIT(n) asm volatile("s_waitcnt vmcnt(" #n ")" ::: "memory")
__device__ __forceinline__ void vfence() { asm volatile("s_waitcnt vmcnt(0)" ::: "memory"); }
__device__ __forceinline__ i32x4 pass(i32x4 v) { asm volatile("" : "+v"(v)); return v; }

__device__ __forceinline__ void cst32(void* p, unsigned int v) {
  __hip_atomic_store((unsigned int*)p, v, __ATOMIC_RELAXED, __HIP_MEMORY_SCOPE_AGENT);
}
__device__ __forceinline__ void cstf(float* p, float v) {
  __hip_atomic_store(p, v, __ATOMIC_RELAXED, __HIP_MEMORY_SCOPE_AGENT);
}
__device__ __forceinline__ int imin4(int a, int b, int c, int d) {
  int x = a < b ? a : b;
  int y = c < d ? c : d;
  return x < y ? x : y;
}

__launch_bounds__(512, 1)
__global__ void lstm_persist(const float* __restrict__ inp,
                             const float* __restrict__ Wx,
                             const float* __restrict__ Wh,
                             const float* __restrict__ bias,
                             const float* __restrict__ Wd,
                             const float* __restrict__ bdp,
                             float* __restrict__ out,
                             unsigned char* __restrict__ ws)
{
  extern __shared__ char smem[];
  f16*   Wl     = (f16*)smem;                    // 131072 B, B-frag swizzled
  float* z_lds  = (float*)(smem + 131072);       // 64 x 68 fp32 = 17408 B
  float* x_sh   = z_lds + 64 * 68;               // 64 x 2
  float* mask_sh= x_sh + 128;                    // 64
  float* wx0_sh = mask_sh + 64;                  // 64
  float* wx1_sh = wx0_sh + 64;                   // 64
  float* b_sh   = wx1_sh + 64;                   // 64
  float* wd_sh  = b_sh + 64;                     // 32
  f16*   hsh    = (f16*)(wd_sh + 32);            // 64 row x 16 u f16 = 2048 B
  float* pps    = (float*)(hsh + 1024);          // 64 row x 2 f32 = 512 B

  const int tid  = threadIdx.x;
  const int bx   = blockIdx.x;
  const int mg   = bx >> 6;         // 4 batch groups of 64 rows (independent LSTMs)
  const int nblk = bx & 63;         // 64 unit-groups of 16 units
  const int ublk = nblk * UPB;

  // ---------------- prologue: stage Wh slice into LDS in B-fragment order ----------------
  {
    const int wrow = tid >> 6;           // 0..7
    const int l    = tid & 63;
    const int gate = l >> 4;
    const int u    = l & 15;
    const int gcol = gate * HH + ublk + u;
    for (int rb = 0; rb < 128; rb += 8) {
      float v[8];
#pragma unroll
      for (int ii = 0; ii < 8; ++ii) {
        int r = (rb + ii) * 8 + wrow;
        v[ii] = Wh[r * FOURH + gcol];
      }
#pragma unroll
      for (int ii = 0; ii < 8; ++ii) {
        int r = (rb + ii) * 8 + wrow;
        int kk = r >> 5, sub = r & 31, q = sub >> 3, j = sub & 7;
        Wl[((kk * 4 + gate) * 64 + (q * 16 + u)) * 8 + j] = (f16)v[ii];
      }
    }
    if (tid < 64) {
      int g2 = tid >> 4, u2 = tid & 15;
      int gc = g2 * HH + ublk + u2;
      wx0_sh[tid] = Wx[gc];
      wx1_sh[tid] = Wx[FOURH + gc];
      b_sh[tid]   = bias[gc];
    }
    if (tid < UPB) {
      wd_sh[tid * 2 + 0] = Wd[(ublk + tid) * 2 + 0];
      wd_sh[tid * 2 + 1] = Wd[(ublk + tid) * 2 + 1];
    }
  }
  __syncthreads();

  // phase-C ownership: unit u_ep, rows r0 and r0+32
  const int u_ep = tid & 15;
  const int r0   = tid >> 4;           // 0..31
  float c_reg[2] = {0.f, 0.f};
  float h_reg[2] = {0.f, 0.f};

  const int wid  = tid >> 6;           // 0..7
  const int kh   = wid & 3;            // k-quarter: 256 k each
  const int mh   = wid >> 2;           // row-half: 32 rows each
  const int lane = tid & 63;
  const int lm   = lane & 15;
  const int lq   = lane >> 4;

  const float bd0 = bdp[0], bd1 = bdp[1];

  for (int s = 0; s < NSTEP; ++s) {
    const bool decode = (s >= 128);

    // ---- coherence epoch: every 8 steps drop (clean) L1 + this XCD's L2 lines.
    // Write-through global stores mean no dirty data can be lost.
    if ((s & 7) == 0) {
      if (wid == 0) {
        asm volatile("buffer_inv sc1" ::: "memory");
        vfence();
      }
      __syncthreads();
    }

    // ---------------- phase A-issue: pred-partial loads (decode, all 512 threads) -------
    // pp slot written at step s-1 is (s-1)&7 == (s+7)&7; read via CACHED loads (L2-shared
    // across the 32 blocks/XCD after first touch; same ring-inv safety as hx).
    i32x4 ppv[4];
    if (decode) {
      const char* pb = (const char*)ws + PP_OFF
                     + (size_t)((((s + 7) & 7) * 4 + mg) * 64) * 512 + r0 * 16;
#pragma unroll
      for (int i = 0; i < 4; ++i) ppv[i] = cld16(pb + (u_ep + 16 * i) * 512);
    } else {
      if (tid < 64) {
        int row = tid;
        const float* ip = inp + ((mg * 64 + row) * TT + (WARM + s)) * 2;
        float i0 = ip[0], i1 = ip[1];
        bool m = (i0 != -1.0f) || (i1 != -1.0f);
        x_sh[row * 2 + 0] = m ? i0 : 0.0f;
        x_sh[row * 2 + 1] = m ? i1 : 0.0f;
        mask_sh[row]      = m ? 1.0f : 0.0f;
      }
    }

    // ---------------- A-fragments: cached 16B loads from ring slot s&7 ----------------
    // wave (kh,mh) = rows 32*mh..+32, k in [256*kh, 256*kh+256)
    i32x4 q[16];
    {
      const char* ab0 = (const char*)ws + (s & 7) * HX_SLOT + mg * 131072
                      + (kh * 16 + (lq >> 1)) * 2048 + (32 * mh + lm) * 32 + (lq & 1) * 16;
      const char* ab1 = ab0 + 16 * 32;
#pragma unroll
      for (int ks = 0; ks < 8; ++ks) {
        q[ks * 2 + 0] = cld16(ab0 + ks * 4096);
        q[ks * 2 + 1] = cld16(ab1 + ks * 4096);
      }
    }

    // ---------------- phase A-complete: pred reduce (hides under A fill) ----------------
    if (decode) {
      VWAIT(16);                     // 4 oldest (pp) done; 16 A-loads still in flight
      f32x4 v = __builtin_bit_cast(f32x4, pass(ppv[0]));
      v += __builtin_bit_cast(f32x4, pass(ppv[1]));
      v += __builtin_bit_cast(f32x4, pass(ppv[2]));
      v += __builtin_bit_cast(f32x4, pass(ppv[3]));
#pragma unroll
      for (int m2 = 1; m2 < 16; m2 <<= 1) {
        v.x += __shfl_xor(v.x, m2, 64);
        v.y += __shfl_xor(v.y, m2, 64);
        v.z += __shfl_xor(v.z, m2, 64);
        v.w += __shfl_xor(v.w, m2, 64);
      }
      if (u_ep == 0) {               // rows 2*r0, 2*r0+1, both outputs
        v.x += bd0; v.y += bd1; v.z += bd0; v.w += bd1;
        *(f32x4*)(x_sh + r0 * 4) = v;
        if (nblk == 0) {
          float* o = out + (size_t)((mg * 64 + 2 * r0) * 128 + (s - 128)) * 2;
          cstf(o, v.x); cstf(o + 1, v.y); cstf(o + 256, v.z); cstf(o + 257, v.w);
        }
      }
      if (s == NSTEP - 1) break;     // uniform across the whole grid
    }

    // ---------------- phase B: MFMA, graded vmcnt (compute ks0-3 while ks4-7 fill) -----
    f32x4 acc[2][4];
#pragma unroll
    for (int m = 0; m < 2; ++m)
#pragma unroll
      for (int n = 0; n < 4; ++n) acc[m][n] = f32x4{0.f, 0.f, 0.f, 0.f};

    VWAIT(8);                        // q[0..7] (ks 0..3) resident
#pragma unroll
    for (int ks = 0; ks < 4; ++ks) {
      const f16* bb = Wl + (kh * 8 + ks) * 2048 + lane * 8;
      f16x8 b0 = *(const f16x8*)(bb);
      f16x8 b1 = *(const f16x8*)(bb + 512);
      f16x8 b2 = *(const f16x8*)(bb + 1024);
      f16x8 b3 = *(const f16x8*)(bb + 1536);
#pragma unroll
      for (int m = 0; m < 2; ++m) {
        f16x8 a = __builtin_bit_cast(f16x8, pass(q[ks * 2 + m]));
        acc[m][0] = __builtin_amdgcn_mfma_f32_16x16x32_f16(a, b0, acc[m][0], 0, 0, 0);
        acc[m][1] = __builtin_amdgcn_mfma_f32_16x16x32_f16(a, b1, acc[m][1], 0, 0, 0);
        acc[m][2] = __builtin_amdgcn_mfma_f32_16x16x32_f16(a, b2, acc[m][2], 0, 0, 0);
        acc[m][3] = __builtin_amdgcn_mfma_f32_16x16x32_f16(a, b3, acc[m][3], 0, 0, 0);
      }
    }
    VWAIT(0);                        // q[8..15] resident
#pragma unroll
    for (int ks = 4; ks < 8; ++ks) {
      const f16* bb = Wl + (kh * 8 + ks) * 2048 + lane * 8;
      f16x8 b0 = *(const f16x8*)(bb);
      f16x8 b1 = *(const f16x8*)(bb + 512);
      f16x8 b2 = *(const f16x8*)(bb + 1024);
      f16x8 b3 = *(const f16x8*)(bb + 1536);
#pragma unroll
      for (int m = 0; m < 2; ++m) {
        f16x8 a = __builtin_bit_cast(f16x8, pass(q[ks * 2 + m]));
        acc[m][0] = __builtin_amdgcn_mfma_f32_16x16x32_f16(a, b0, acc[m][0], 0, 0, 0);
        acc[m][1] = __builtin_amdgcn_mfma_f32_16x16x32_f16(a, b1, acc[m][1], 0, 0, 0);
        acc[m][2] = __builtin_amdgcn_mfma_f32_16x16x32_f16(a, b2, acc[m][2], 0, 0, 0);
        acc[m][3] = __builtin_amdgcn_mfma_f32_16x16x32_f16(a, b3, acc[m][3], 0, 0, 0);
      }
    }

    // ---------------- z merge: 4 sequential k-quarter stages (race-free by rows) --------
    // C/D layout: row = 32*mh + 16*m + 4*lq + reg, col = 16*n + lm
#pragma unroll
    for (int stage = 0; stage < 4; ++stage) {
      if (kh == stage) {
#pragma unroll
        for (int m = 0; m < 2; ++m) {
          const int rb = 32 * mh + 16 * m + 4 * lq;
#pragma unroll
          for (int n = 0; n < 4; ++n) {
#pragma unroll
            for (int r = 0; r < 4; ++r) {
              float* zp = &z_lds[(rb + r) * 68 + 16 * n + lm];
              if (stage == 0) *zp = acc[m][n][r];
              else            *zp += acc[m][n][r];
            }
          }
        }
      }
      __syncthreads();
    }

    // ---------------- phase C: gates + state update ----------------
    const bool wr_pred = (s >= 127);
#pragma unroll
    for (int q4 = 0; q4 < 2; ++q4) {
      int row = r0 + 32 * q4;
      float x0 = x_sh[row * 2], x1 = x_sh[row * 2 + 1];
      float* zr = z_lds + row * 68;
      float zi = zr[     u_ep] + x0 * wx0_sh[     u_ep] + x1 * wx1_sh[     u_ep] + b_sh[     u_ep];
      float zf = zr[16 + u_ep] + x0 * wx0_sh[16 + u_ep] + x1 * wx1_sh[16 + u_ep] + b_sh[16 + u_ep];
      float zg = zr[32 + u_ep] + x0 * wx0_sh[32 + u_ep] + x1 * wx1_sh[32 + u_ep] + b_sh[32 + u_ep];
      float zo = zr[48 + u_ep] + x0 * wx0_sh[48 + u_ep] + x1 * wx1_sh[48 + u_ep] + b_sh[48 + u_ep];
      float ig = fsig(zi), fg = fsig(zf), gg = ftanh(zg), og = fsig(zo);
      float cn = fg * c_reg[q4] + ig * gg;
      float hn = og * ftanh(cn);
      if (!decode) {
        bool m = mask_sh[row] > 0.5f;
        cn = m ? cn : c_reg[q4];
        hn = m ? hn : h_reg[q4];
      }
      c_reg[q4] = cn; h_reg[q4] = hn;

      hsh[row * 16 + u_ep] = (f16)hn;

      if (wr_pred) {
        float p0 = hn * wd_sh[u_ep * 2 + 0];
        float p1 = hn * wd_sh[u_ep * 2 + 1];
#pragma unroll
        for (int m2 = 1; m2 < 16; m2 <<= 1) {
          p0 += __shfl_xor(p0, m2, 64);
          p1 += __shfl_xor(p1, m2, 64);
        }
        if (u_ep == 0) { pps[row * 2] = p0; pps[row * 2 + 1] = p1; }
      }
    }

    // ---------------- per-wave self-bounce: wave w bounces ONLY rows its own lanes
    // ---------------- wrote to hsh/pps (rows 4w..4w+3, 4w+32..35) -> no __syncthreads
    asm volatile("" ::: "memory");                 // keep LDS writes above the reads
    {
      if (lane < 16) {
        int idx = lane >> 1, oct = lane & 1;
        int row = (idx < 4) ? (4 * wid + idx) : (28 + 4 * wid + idx);
        f16x8 hv = *(const f16x8*)(hsh + row * 16 + oct * 8);
        char* dst = (char*)ws + ((s + 1) & 7) * HX_SLOT + mg * 131072 + nblk * 2048
                  + row * 32 + oct * 16;
        ast16(dst, __builtin_bit_cast(i32x4, hv));
      }
      if (wr_pred && lane < 4) {
        int row = (lane < 2) ? (4 * wid + 2 * lane) : (4 * wid + 32 + 2 * (lane - 2));
        f32x4 pv = *(const f32x4*)(pps + row * 2);
        char* dst = (char*)ws + PP_OFF + (size_t)(((s & 7) * 4 + mg) * 64 + nblk) * 512
                  + row * 8;
        ast16(dst, __builtin_bit_cast(i32x4, pv));
      }
      vfence();                                    // drain this wave's stores
    }
    __syncthreads();                               // all waves' stores drained

    // ---------------- per-mg barrier: 64 flags, wide agent-load poll ----------------
    {
      unsigned int* fl = (unsigned int*)((char*)ws + FLG_OFF + mg * 1024);
      if (tid == 0) cst32(fl + nblk, (unsigned int)(s + 1));
      if (tid < 16) {
        const char* fp = (const char*)fl + tid * 16;
        const int tgt = s + 1;
        int guard = 0;
        for (;;) {
          i32x4 f = ald16(fp);
          vfence();
          f = pass(f);
          int mn = imin4(f.x, f.y, f.z, f.w);
          if (__all(mn >= tgt)) break;
          if (++guard > 200000) break;             // bail-out: never hang the bench
          __builtin_amdgcn_s_sleep(1);
        }
      }
      __syncthreads();
    }
  }
  vfence();
}

extern "C" void kernel_launch(void* const* d_in, const int* in_sizes, int n_in,
                              void* d_out, int out_size, void* d_ws, size_t ws_size,
                              hipStream_t stream) {
  const float* inp = (const float*)d_in[0];
  const float* Wx  = (const float*)d_in[1];
  const float* Wh  = (const float*)d_in[2];
  const float* b   = (const float*)d_in[3];
  const float* Wd  = (const float*)d_in[4];
  const float* bd  = (const float*)d_in[5];
  float* out = (float*)d_out;
  unsigned char* ws = (unsigned char*)d_ws;

  init_ws<<<517, 256, 0, stream>>>((unsigned int*)ws);

  hipFuncSetAttribute((const void*)lstm_persist,
                      hipFuncAttributeMaxDynamicSharedMemorySize, LDS_BYTES);
  lstm_persist<<<256, 512, LDS_BYTES, stream>>>(inp, Wx, Wh, b, Wd, bd, out, ws);
}